// Round 2
// baseline (154.142 us; speedup 1.0000x reference)
//
#include <hip/hip_runtime.h>

// ---------------------------------------------------------------------------
// MoE with adaptive gate, B=8192 D=2048 E=8 H=128, fp32 in/out, bf16 MFMA core
// GEMM1/GEMM3: 256x128 tile, 8 waves, BK=64, 2-phase/K-tile counted-vmcnt pipe
// ---------------------------------------------------------------------------

typedef __attribute__((ext_vector_type(8))) short short8;   // 8 bf16 (4 VGPRs)
typedef __attribute__((ext_vector_type(4))) float f32x4;    // MFMA C/D

#define B_SZ 8192
#define D_SZ 2048
#define E_SZ 8
#define H_SZ 128
#define TILE_ELEMS 8192   // frag-ready tile: 128 rows x 64 k, elem = kg*1024 + p*8 + j

#define VMCNT(n) asm volatile("s_waitcnt vmcnt(" #n ")" ::: "memory")
#define LGKM0()  asm volatile("s_waitcnt lgkmcnt(0)" ::: "memory")
#define SB0()    __builtin_amdgcn_sched_barrier(0)
#define BAR()    __builtin_amdgcn_s_barrier()

__device__ __forceinline__ short f2bf(float f) {
  unsigned u = __builtin_bit_cast(unsigned, f);
  unsigned r = (u + 0x7fffu + ((u >> 16) & 1u)) >> 16;   // RNE
  return (short)r;
}

__device__ __forceinline__ float silu_f(float v) {
  return v / (1.f + __expf(-v));
}

__device__ __forceinline__ void gload_lds16(const void* g, void* l) {
  __builtin_amdgcn_global_load_lds(
      (const __attribute__((address_space(1))) void*)g,
      (__attribute__((address_space(3))) void*)l,
      16, 0, 0);
}

// ---------------------------------------------------------------------------
// Pipelined core: BM=256 (row-tiles rt=0,1), BN=128 (one col-tile), BK=64.
// A tile (rt,t) at Ab + (rt*NKT + t)*8192 ; B tile t at Bb + t*8192.
// LDS: [2 buf][ A0(8192) A1(8192) B(8192) ] shorts = 96 KB.
// Per K-tile: phase ks=0 reads kg0-3, ks=1 reads kg4-7.
// Stage unit = K-half of a tile = 3 global_load_lds per thread (A0,A1,B).
// Schedule: (t,ph0) stages K1(t+1)->buf[cur^1]; (t,ph1) stages K0(t+2)->buf[cur].
// vmcnt(6) at each phase end retires the K-half needed by the next phase.
// ---------------------------------------------------------------------------
template<int NKT>
__device__ __forceinline__ void core8(const short* __restrict__ Ab,
                                      const short* __restrict__ Bb,
                                      short* lds, f32x4 acc[4][4])
{
  const int tid  = threadIdx.x;
  const int lane = tid & 63;
  const int wid  = tid >> 6;
  const int wm = wid >> 1, wn = wid & 1;     // 4 x 2 wave grid, wave = 64x64
  const int rt = wm >> 1, rh = wm & 1;
  const int lm = lane & 15, lk = lane >> 4;
  const int wlds = (tid & ~63) * 8;          // wave-uniform LDS offset (shorts)

  auto STAGE = [&](int b, int tau, int kh) {   // 3 loads/thread
    const int boff = b * 24576;
    gload_lds16(Ab + (size_t)(0*NKT + tau)*8192 + kh*4096 + tid*8,
                lds + boff + 0*8192 + kh*4096 + wlds);
    gload_lds16(Ab + (size_t)(1*NKT + tau)*8192 + kh*4096 + tid*8,
                lds + boff + 1*8192 + kh*4096 + wlds);
    gload_lds16(Bb + (size_t)tau*8192 + kh*4096 + tid*8,
                lds + boff + 16384 + kh*4096 + wlds);
  };
  auto READ_A = [&](int ks, int cur, short8 av[4]) {
    const short* Ac = lds + cur*24576 + rt*8192 + (ks*4+lk)*1024 + (rh*64 + lm)*8;
    #pragma unroll
    for (int f = 0; f < 4; ++f) av[f] = *(const short8*)(Ac + f*128);
  };
  auto READ_B = [&](int ks, int cur, short8 bv[4]) {
    const short* Bc = lds + cur*24576 + 16384 + (ks*4+lk)*1024 + (wn*64 + lm)*8;
    #pragma unroll
    for (int f = 0; f < 4; ++f) bv[f] = *(const short8*)(Bc + f*128);
  };
  auto MFMA16 = [&](short8 av[4], short8 bv[4]) {
    __builtin_amdgcn_s_setprio(1);
    #pragma unroll
    for (int i = 0; i < 4; ++i)
      #pragma unroll
      for (int j = 0; j < 4; ++j)
        acc[i][j] = __builtin_amdgcn_mfma_f32_16x16x32_bf16(av[i], bv[j], acc[i][j], 0, 0, 0);
    __builtin_amdgcn_s_setprio(0);
  };

  // prologue: K0(0), K1(0), K0(1) = 9 loads; vmcnt(6) -> K0(0) landed
  STAGE(0, 0, 0);
  STAGE(0, 0, 1);
  STAGE(1, 1, 0);
  VMCNT(6); BAR();

  for (int t = 0; t < NKT - 2; ++t) {
    const int cur = t & 1;
    short8 av[4], bv[4];
    // phase 0 (ks=0)
    READ_A(0, cur, av); READ_B(0, cur, bv);
    STAGE(cur ^ 1, t + 1, 1);          // K1(t+1)
    BAR(); LGKM0(); SB0();
    MFMA16(av, bv);
    SB0(); VMCNT(6); BAR();            // K1(t) certified for next phase
    // phase 1 (ks=1)
    READ_A(1, cur, av); READ_B(1, cur, bv);
    STAGE(cur, t + 2, 0);              // K0(t+2) into K0 region (dead since ph0 barrier)
    BAR(); LGKM0(); SB0();
    MFMA16(av, bv);
    SB0(); VMCNT(6); BAR();            // K0(t+1) certified
  }
  { // tile NKT-2
    const int cur = (NKT - 2) & 1;
    short8 av[4], bv[4];
    READ_A(0, cur, av); READ_B(0, cur, bv);
    STAGE(cur ^ 1, NKT - 1, 1);        // K1(NKT-1)
    BAR(); LGKM0(); SB0();
    MFMA16(av, bv);
    SB0(); VMCNT(6); BAR();
    READ_A(1, cur, av); READ_B(1, cur, bv);
    BAR(); LGKM0(); SB0();
    MFMA16(av, bv);
    SB0(); VMCNT(3); BAR();            // K0(NKT-1) certified (only K1(NKT-1) in flight)
  }
  { // tile NKT-1
    const int cur = (NKT - 1) & 1;
    short8 av[4], bv[4];
    READ_A(0, cur, av); READ_B(0, cur, bv);
    BAR(); LGKM0(); SB0();
    MFMA16(av, bv);
    SB0(); VMCNT(0); BAR();            // K1(NKT-1) certified; all vmem drained
    READ_A(1, cur, av); READ_B(1, cur, bv);
    BAR(); LGKM0(); SB0();
    MFMA16(av, bv);
    SB0();
  }
}

// ---------------------------------------------------------------------------
// Legacy 128x128 core (kept for the tiny GEMM2, NKT=2)
// ---------------------------------------------------------------------------
template<int NKT>
__device__ __forceinline__ void gemm_core(const short* __restrict__ Ab,
                                          const short* __restrict__ Bb,
                                          short* lds, f32x4 acc[4][4])
{
  const int tid  = threadIdx.x;
  const int lane = tid & 63;
  const int wid  = tid >> 6;
  const int wr = wid >> 1, wc = wid & 1;
  const int lm = lane & 15, lk = lane >> 4;
  const int wbase = tid & ~63;
  short* As = lds;
  short* Bs = lds + 2 * TILE_ELEMS;

  #pragma unroll
  for (int q = 0; q < 4; ++q) {
    gload_lds16(Ab + (q*256 + tid)*8, As + (q*256 + wbase)*8);
    gload_lds16(Bb + (q*256 + tid)*8, Bs + (q*256 + wbase)*8);
  }
  __syncthreads();

  for (int kt = 0; kt < NKT; ++kt) {
    const int cur = kt & 1;
    if (kt + 1 < NKT) {
      const short* ga = Ab + (size_t)(kt+1)*TILE_ELEMS;
      const short* gb = Bb + (size_t)(kt+1)*TILE_ELEMS;
      short* la = As + (cur^1)*TILE_ELEMS;
      short* lb = Bs + (cur^1)*TILE_ELEMS;
      #pragma unroll
      for (int q = 0; q < 4; ++q) {
        gload_lds16(ga + (q*256 + tid)*8, la + (q*256 + wbase)*8);
        gload_lds16(gb + (q*256 + tid)*8, lb + (q*256 + wbase)*8);
      }
    }
    const short* Ac = As + cur*TILE_ELEMS;
    const short* Bc = Bs + cur*TILE_ELEMS;
    #pragma unroll
    for (int ks = 0; ks < 2; ++ks) {
      short8 av[4], bv[4];
      #pragma unroll
      for (int f = 0; f < 4; ++f)
        av[f] = *(const short8*)(Ac + (ks*4 + lk)*1024 + (wr*64 + f*16 + lm)*8);
      #pragma unroll
      for (int f = 0; f < 4; ++f)
        bv[f] = *(const short8*)(Bc + (ks*4 + lk)*1024 + (wc*64 + f*16 + lm)*8);
      #pragma unroll
      for (int i = 0; i < 4; ++i)
        #pragma unroll
        for (int j = 0; j < 4; ++j)
          acc[i][j] = __builtin_amdgcn_mfma_f32_16x16x32_bf16(av[i], bv[j], acc[i][j], 0, 0, 0);
    }
    __syncthreads();
  }
}

// ---------------------------------------------------------------------------
// K0: convert x / W1 / W2 / W3 into bf16 frag-ready layouts.
// ---------------------------------------------------------------------------
__global__ __launch_bounds__(256)
void k_convert(const float* __restrict__ x,  const float* __restrict__ W1,
               const float* __restrict__ W2, const float* __restrict__ W3,
               short* __restrict__ xf, short* __restrict__ w1f,
               short* __restrict__ w2f, short* __restrict__ w3f)
{
  const int gi = blockIdx.x * 256 + threadIdx.x;
  if (gi < 2097152) {                       // xf: A-FR of x [8192][2048]
    const int t = gi >> 10, r = gi & 1023;
    const int bt = t >> 5, kt = t & 31;
    const int kg = r >> 7, p = r & 127;
    const float* src = x + (size_t)(bt*128 + p)*2048 + kt*64 + kg*8;
    const float4 v0 = *(const float4*)src;
    const float4 v1 = *(const float4*)(src + 4);
    short8 o;
    o[0]=f2bf(v0.x); o[1]=f2bf(v0.y); o[2]=f2bf(v0.z); o[3]=f2bf(v0.w);
    o[4]=f2bf(v1.x); o[5]=f2bf(v1.y); o[6]=f2bf(v1.z); o[7]=f2bf(v1.w);
    *(short8*)(xf + (size_t)gi*8) = o;
  } else if (gi < 2097152 + 262144) {       // w1f: B-FR of W1[e] [2048][128]
    const int g = gi - 2097152;
    const int t = g >> 10, r = g & 1023;
    const int e = t >> 5, kt = t & 31;
    const int kg = r >> 7, p = r & 127;
    const int k0 = kt*64 + kg*8;
    short8 o;
    #pragma unroll
    for (int j = 0; j < 8; ++j)
      o[j] = f2bf(W1[(size_t)e*262144 + (size_t)(k0 + j)*128 + p]);
    *(short8*)(w1f + (size_t)g*8) = o;
  } else if (gi < 2097152 + 262144 + 16384) { // w2f: B-FR of W2[e] [128][128]
    const int g = gi - (2097152 + 262144);
    const int t = g >> 10, r = g & 1023;
    const int e = t >> 1, kt = t & 1;
    const int kg = r >> 7, p = r & 127;
    const int k0 = kt*64 + kg*8;
    short8 o;
    #pragma unroll
    for (int j = 0; j < 8; ++j)
      o[j] = f2bf(W2[(size_t)e*16384 + (size_t)(k0 + j)*128 + p]);
    *(short8*)(w2f + (size_t)g*8) = o;
  } else if (gi < 2637824) {                // w3f: B-FR of W3 flat [1024][2048]
    const int g = gi - 2375680;
    const int t = g >> 10, r = g & 1023;
    const int nt = t >> 4, kt = t & 15;
    const int kg = r >> 7, p = r & 127;
    const int k0 = kt*64 + kg*8;
    short8 o;
    #pragma unroll
    for (int j = 0; j < 8; ++j) {
      const int k = k0 + j;                 // k = e*128 + h
      o[j] = f2bf(W3[(size_t)(k >> 7)*262144 + (size_t)(k & 127)*2048 + nt*128 + p]);
    }
    *(short8*)(w3f + (size_t)g*8) = o;
  }
}

// ---------------------------------------------------------------------------
// K1: gate softmax.  One wave per row, fp32 end-to-end.
// ---------------------------------------------------------------------------
__global__ __launch_bounds__(256)
void k_gate(const float* __restrict__ x, const float* __restrict__ gw,
            const float* __restrict__ gb, float* __restrict__ gates)
{
  const int wid = threadIdx.x >> 6, lane = threadIdx.x & 63;
  const int row = blockIdx.x * 4 + wid;
  const float* xr = x + (size_t)row * 2048;
  float acc[8] = {0.f,0.f,0.f,0.f,0.f,0.f,0.f,0.f};
  for (int it = 0; it < 32; ++it) {
    const int k = it*64 + lane;
    const float xv = xr[k];
    const float4 g0 = *(const float4*)(gw + (size_t)k*8);
    const float4 g1 = *(const float4*)(gw + (size_t)k*8 + 4);
    acc[0] += xv*g0.x; acc[1] += xv*g0.y; acc[2] += xv*g0.z; acc[3] += xv*g0.w;
    acc[4] += xv*g1.x; acc[5] += xv*g1.y; acc[6] += xv*g1.z; acc[7] += xv*g1.w;
  }
  #pragma unroll
  for (int e = 0; e < 8; ++e) {
    #pragma unroll
    for (int d = 1; d < 64; d <<= 1)
      acc[e] += __shfl_xor(acc[e], d, 64);
  }
  if (lane == 0) {
    float lg[8], mx = -1e30f;
    #pragma unroll
    for (int e = 0; e < 8; ++e) { lg[e] = acc[e] + gb[e]; mx = fmaxf(mx, lg[e]); }
    float s = 0.f;
    #pragma unroll
    for (int e = 0; e < 8; ++e) { lg[e] = __expf(lg[e] - mx); s += lg[e]; }
    const float inv = 1.f / s;
    #pragma unroll
    for (int e = 0; e < 8; ++e) gates[(size_t)row*8 + e] = lg[e] * inv;
  }
}

// ---------------------------------------------------------------------------
// K2: h1[e] = silu(x @ W1[e] + b1[e]) -> frag-ready bf16.  256x128 pipelined.
// grid (32, 8)
// ---------------------------------------------------------------------------
__global__ __launch_bounds__(512, 2)
void k_gemm1(const short* __restrict__ xf, const short* __restrict__ w1f,
             const float* __restrict__ b1, short* __restrict__ h1f)
{
  __shared__ short lds[49152];   // 96 KB
  const int bt = blockIdx.x, e = blockIdx.y;
  f32x4 acc[4][4] = {};
  core8<32>(xf + (size_t)(bt*2)*32*8192, w1f + (size_t)e*32*8192, lds, acc);

  __syncthreads();
  const int tid = threadIdx.x, lane = tid & 63, wid = tid >> 6;
  const int wm = wid >> 1, wn = wid & 1, lm = lane & 15, lr = lane >> 4;
  float bv[4];
  #pragma unroll
  for (int fn = 0; fn < 4; ++fn) bv[fn] = b1[e*H_SZ + wn*64 + fn*16 + lm];
  #pragma unroll
  for (int fm = 0; fm < 4; ++fm)
  #pragma unroll
  for (int i = 0; i < 4; ++i) {
    const int m = wm*64 + fm*16 + lr*4 + i;       // 0..255
    #pragma unroll
    for (int fn = 0; fn < 4; ++fn) {
      const int n = wn*64 + fn*16 + lm;           // 0..127
      float v = silu_f(acc[fm][fn][i] + bv[fn]);
      // LDS frag-ready: [rt][kt][kg][p][j]
      lds[(m>>7)*16384 + (n>>6)*8192 + ((n>>3)&7)*1024 + (m&127)*8 + (n&7)] = f2bf(v);
    }
  }
  __syncthreads();
  #pragma unroll
  for (int q = 0; q < 8; ++q) {
    const int li = q*4096 + tid*8;
    const int ti = li >> 13, o = li & 8191;
    const int rt_o = ti >> 1, kt_o = ti & 1;
    short* dst = h1f + ((size_t)(e*64 + bt*2 + rt_o)*2 + kt_o)*8192 + o;
    *(short8*)dst = *(const short8*)(lds + li);
  }
}

// ---------------------------------------------------------------------------
// K3: h2g[e] = gates[:,e] * silu(h1[e] @ W2[e] + b2[e]) -> frag-ready bf16
// (unchanged legacy 128x128 core; K=128 only).  grid (64, 8)
// ---------------------------------------------------------------------------
__global__ __launch_bounds__(256, 2)
void k_gemm2(const short* __restrict__ h1f, const short* __restrict__ w2f,
             const float* __restrict__ b2, const float* __restrict__ gates,
             short* __restrict__ h2gf)
{
  __shared__ short lds[4 * TILE_ELEMS];
  const int bt = blockIdx.x, e = blockIdx.y;
  f32x4 acc[4][4] = {};
  gemm_core<2>(h1f + (size_t)e*1048576 + (size_t)bt*16384,
               w2f + (size_t)e*2*TILE_ELEMS, lds, acc);

  const int tid = threadIdx.x, lane = tid & 63, wid = tid >> 6;
  const int wr = wid >> 1, wc = wid & 1, lm = lane & 15;
  float bv[4];
  #pragma unroll
  for (int fn = 0; fn < 4; ++fn) bv[fn] = b2[e*H_SZ + wc*64 + fn*16 + lm];
  #pragma unroll
  for (int fm = 0; fm < 4; ++fm)
  #pragma unroll
  for (int i = 0; i < 4; ++i) {
    const int m = wr*64 + fm*16 + (lane>>4)*4 + i;
    const float g = gates[(size_t)(bt*128 + m)*8 + e];
    #pragma unroll
    for (int fn = 0; fn < 4; ++fn) {
      const int n = wc*64 + fn*16 + lm;
      float v = silu_f(acc[fm][fn][i] + bv[fn]) * g;
      lds[(n>>6)*TILE_ELEMS + ((n>>3)&7)*1024 + m*8 + (n&7)] = f2bf(v);
    }
  }
  __syncthreads();
  short* gout = h2gf + (size_t)bt*16384*8 + (size_t)e*16384;
  #pragma unroll
  for (int q = 0; q < 8; ++q) {
    const int li = q*256 + tid;
    *(short8*)(gout + li*8) = *(const short8*)(lds + li*8);
  }
}

// ---------------------------------------------------------------------------
// K4: out = h2g @ W3flat + gates @ b3.  256x128 pipelined.  grid (32, 16)
// ---------------------------------------------------------------------------
__global__ __launch_bounds__(512, 2)
void k_gemm3(const short* __restrict__ h2gf, const short* __restrict__ w3f,
             const float* __restrict__ b3, const float* __restrict__ gates,
             float* __restrict__ out)
{
  __shared__ short lds[49152];   // 96 KB
  const int bt = blockIdx.x, nt = blockIdx.y;
  f32x4 acc[4][4] = {};
  core8<16>(h2gf + (size_t)(bt*2)*16*8192, w3f + (size_t)nt*16*8192, lds, acc);

  const int tid = threadIdx.x, lane = tid & 63, wid = tid >> 6;
  const int wm = wid >> 1, wn = wid & 1, lm = lane & 15, lr = lane >> 4;
  float b3c[4][8];
  #pragma unroll
  for (int fn = 0; fn < 4; ++fn) {
    const int n = nt*128 + wn*64 + fn*16 + lm;
    #pragma unroll
    for (int e = 0; e < 8; ++e) b3c[fn][e] = b3[(size_t)e*D_SZ + n];
  }
  #pragma unroll
  for (int fm = 0; fm < 4; ++fm)
  #pragma unroll
  for (int i = 0; i < 4; ++i) {
    const int m = bt*256 + wm*64 + fm*16 + lr*4 + i;
    const float4 ga  = *(const float4*)(gates + (size_t)m*8);
    const float4 gbv = *(const float4*)(gates + (size_t)m*8 + 4);
    #pragma unroll
    for (int fn = 0; fn < 4; ++fn) {
      const int n = nt*128 + wn*64 + fn*16 + lm;
      const float bias = ga.x*b3c[fn][0] + ga.y*b3c[fn][1] + ga.z*b3c[fn][2] + ga.w*b3c[fn][3]
                       + gbv.x*b3c[fn][4] + gbv.y*b3c[fn][5] + gbv.z*b3c[fn][6] + gbv.w*b3c[fn][7];
      out[(size_t)m*D_SZ + n] = acc[fm][fn][i] + bias;
    }
  }
}

// ---------------------------------------------------------------------------
extern "C" void kernel_launch(void* const* d_in, const int* in_sizes, int n_in,
                              void* d_out, int out_size, void* d_ws, size_t ws_size,
                              hipStream_t stream)
{
  (void)in_sizes; (void)n_in; (void)out_size; (void)ws_size;
  const float* x  = (const float*)d_in[0];
  const float* gw = (const float*)d_in[1];
  const float* gb = (const float*)d_in[2];
  const float* W1 = (const float*)d_in[3];
  const float* b1 = (const float*)d_in[4];
  const float* W2 = (const float*)d_in[5];
  const float* b2 = (const float*)d_in[6];
  const float* W3 = (const float*)d_in[7];
  const float* b3 = (const float*)d_in[8];
  float* out = (float*)d_out;

  char* ws = (char*)d_ws;
  short* xf    = (short*)ws;  ws += (size_t)B_SZ*D_SZ*2;
  short* w1f   = (short*)ws;  ws += (size_t)E_SZ*D_SZ*H_SZ*2;
  short* w2f   = (short*)ws;  ws += (size_t)E_SZ*H_SZ*H_SZ*2;
  short* w3f   = (short*)ws;  ws += (size_t)E_SZ*H_SZ*D_SZ*2;
  float* gates = (float*)ws;  ws += (size_t)B_SZ*E_SZ*4;
  short* h1f   = (short*)ws;  ws += (size_t)E_SZ*B_SZ*H_SZ*2;
  short* h2gf  = (short*)ws;  ws += (size_t)B_SZ*E_SZ*H_SZ*2;

  k_convert<<<dim3(10304), dim3(256), 0, stream>>>(x, W1, W2, W3, xf, w1f, w2f, w3f);
  k_gate   <<<dim3(2048),  dim3(256), 0, stream>>>(x, gw, gb, gates);
  k_gemm1  <<<dim3(32, 8),  dim3(512), 0, stream>>>(xf, w1f, b1, h1f);
  k_gemm2  <<<dim3(64, 8),  dim3(256), 0, stream>>>(h1f, w2f, b2, gates, h2gf);
  k_gemm3  <<<dim3(32, 16), dim3(512), 0, stream>>>(h2gf, w3f, b3, gates, out);
}

// Round 3
// 141.064 us; speedup vs baseline: 1.0927x; 1.0927x over previous
//
#include <hip/hip_runtime.h>

// ---------------------------------------------------------------------------
// MoE with adaptive gate, B=8192 D=2048 E=8 H=128, fp32 in/out, bf16 MFMA core
// GEMM1 merged over experts (N=1024) + fused GEMM2 + gate-scale epilogue.
// GEMM3 at 256x256. Both use a 2-subphase/K-tile counted-vmcnt core and
// 2D XCD-chunked block mapping for L2 residency.
// ---------------------------------------------------------------------------

typedef __attribute__((ext_vector_type(8))) short short8;   // 8 bf16 (4 VGPRs)
typedef __attribute__((ext_vector_type(4))) float f32x4;    // MFMA C/D

#define B_SZ 8192
#define D_SZ 2048
#define E_SZ 8
#define H_SZ 128

#define VMCNT(n) asm volatile("s_waitcnt vmcnt(" #n ")" ::: "memory")
#define BAR()    __builtin_amdgcn_s_barrier()

__device__ __forceinline__ short f2bf(float f) {
  unsigned u = __builtin_bit_cast(unsigned, f);
  unsigned r = (u + 0x7fffu + ((u >> 16) & 1u)) >> 16;   // RNE
  return (short)r;
}

__device__ __forceinline__ float silu_f(float v) {
  return v / (1.f + __expf(-v));
}

__device__ __forceinline__ void gload_lds16(const void* g, void* l) {
  __builtin_amdgcn_global_load_lds(
      (const __attribute__((address_space(1))) void*)g,
      (__attribute__((address_space(3))) void*)l,
      16, 0, 0);
}

// ---------------------------------------------------------------------------
// K0: convert x / W1 / W2 / W3 into bf16 frag-ready layouts.
// frag-ready sub-tile = 8192 shorts: elem = kg*1024 + p*8 + j  (p=row/col, 128)
// ---------------------------------------------------------------------------
__global__ __launch_bounds__(256)
void k_convert(const float* __restrict__ x,  const float* __restrict__ W1,
               const float* __restrict__ W2, const float* __restrict__ W3,
               short* __restrict__ xf, short* __restrict__ w1f,
               short* __restrict__ w2f, short* __restrict__ w3f)
{
  const int gi = blockIdx.x * 256 + threadIdx.x;
  if (gi < 2097152) {                       // xf: [bt64][kt32] tiles of x
    const int t = gi >> 10, r = gi & 1023;
    const int bt = t >> 5, kt = t & 31;
    const int kg = r >> 7, p = r & 127;
    const float* src = x + (size_t)(bt*128 + p)*2048 + kt*64 + kg*8;
    const float4 v0 = *(const float4*)src;
    const float4 v1 = *(const float4*)(src + 4);
    short8 o;
    o[0]=f2bf(v0.x); o[1]=f2bf(v0.y); o[2]=f2bf(v0.z); o[3]=f2bf(v0.w);
    o[4]=f2bf(v1.x); o[5]=f2bf(v1.y); o[6]=f2bf(v1.z); o[7]=f2bf(v1.w);
    *(short8*)(xf + (size_t)gi*8) = o;
  } else if (gi < 2097152 + 262144) {       // w1f: [e8][kt32] tiles of W1[e] (col p=h)
    const int g = gi - 2097152;
    const int t = g >> 10, r = g & 1023;
    const int e = t >> 5, kt = t & 31;
    const int kg = r >> 7, p = r & 127;
    const int k0 = kt*64 + kg*8;
    short8 o;
    #pragma unroll
    for (int j = 0; j < 8; ++j)
      o[j] = f2bf(W1[(size_t)e*262144 + (size_t)(k0 + j)*128 + p]);
    *(short8*)(w1f + (size_t)g*8) = o;
  } else if (gi < 2097152 + 262144 + 16384) { // w2f: [e8][kt2] tiles of W2[e]
    const int g = gi - (2097152 + 262144);
    const int t = g >> 10, r = g & 1023;
    const int e = t >> 1, kt = t & 1;
    const int kg = r >> 7, p = r & 127;
    const int k0 = kt*64 + kg*8;
    short8 o;
    #pragma unroll
    for (int j = 0; j < 8; ++j)
      o[j] = f2bf(W2[(size_t)e*16384 + (size_t)(k0 + j)*128 + p]);
    *(short8*)(w2f + (size_t)g*8) = o;
  } else if (gi < 2637824) {                // w3f: [nt16][kt16] tiles of W3flat
    const int g = gi - 2375680;
    const int t = g >> 10, r = g & 1023;
    const int nt = t >> 4, kt = t & 15;
    const int kg = r >> 7, p = r & 127;
    const int k0 = kt*64 + kg*8;
    short8 o;
    #pragma unroll
    for (int j = 0; j < 8; ++j) {
      const int k = k0 + j;                 // k = e*128 + h
      o[j] = f2bf(W3[(size_t)(k >> 7)*262144 + (size_t)(k & 127)*2048 + nt*128 + p]);
    }
    *(short8*)(w3f + (size_t)g*8) = o;
  }
}

// ---------------------------------------------------------------------------
// K1: gate softmax.  One wave per row, fp32 end-to-end.
// ---------------------------------------------------------------------------
__global__ __launch_bounds__(256)
void k_gate(const float* __restrict__ x, const float* __restrict__ gw,
            const float* __restrict__ gb, float* __restrict__ gates)
{
  const int wid = threadIdx.x >> 6, lane = threadIdx.x & 63;
  const int row = blockIdx.x * 4 + wid;
  const float* xr = x + (size_t)row * 2048;
  float acc[8] = {0.f,0.f,0.f,0.f,0.f,0.f,0.f,0.f};
  for (int it = 0; it < 32; ++it) {
    const int k = it*64 + lane;
    const float xv = xr[k];
    const float4 g0 = *(const float4*)(gw + (size_t)k*8);
    const float4 g1 = *(const float4*)(gw + (size_t)k*8 + 4);
    acc[0] += xv*g0.x; acc[1] += xv*g0.y; acc[2] += xv*g0.z; acc[3] += xv*g0.w;
    acc[4] += xv*g1.x; acc[5] += xv*g1.y; acc[6] += xv*g1.z; acc[7] += xv*g1.w;
  }
  #pragma unroll
  for (int e = 0; e < 8; ++e) {
    #pragma unroll
    for (int d = 1; d < 64; d <<= 1)
      acc[e] += __shfl_xor(acc[e], d, 64);
  }
  if (lane == 0) {
    float lg[8], mx = -1e30f;
    #pragma unroll
    for (int e = 0; e < 8; ++e) { lg[e] = acc[e] + gb[e]; mx = fmaxf(mx, lg[e]); }
    float s = 0.f;
    #pragma unroll
    for (int e = 0; e < 8; ++e) { lg[e] = __expf(lg[e] - mx); s += lg[e]; }
    const float inv = 1.f / s;
    #pragma unroll
    for (int e = 0; e < 8; ++e) gates[(size_t)row*8 + e] = lg[e] * inv;
  }
}

// ---------------------------------------------------------------------------
// K2: fused GEMM1 + silu + GEMM2 + silu + gate-scale -> h2gf frag-ready.
// BM=128 rows, BN=256 cols (expert pair), K=2048.  512 thr, 8 waves (2Mx4N),
// wave-out 64x64.  LDS 128KB: core bufs 2x48KB + epilogue reuse.
// grid: 256 blocks, XCD-chunked: xcd=wg&7, idx=wg>>3, bt=xcd*8+(idx>>2), nt=idx&3.
// ---------------------------------------------------------------------------
__global__ __launch_bounds__(512, 2)
void k_gemm12(const short* __restrict__ xf, const short* __restrict__ w1f,
              const short* __restrict__ w2f,
              const float* __restrict__ b1, const float* __restrict__ b2,
              const float* __restrict__ gates, short* __restrict__ h2gf)
{
  __shared__ short lds[65536];   // 128 KB
  const int wg = blockIdx.x;
  const int xcd = wg & 7, idx = wg >> 3;
  const int bt = xcd*8 + (idx >> 2);      // 0..63   (B-panels L2-resident per XCD)
  const int nt = idx & 3;                 // 0..3    (expert pair 2nt, 2nt+1)

  const int tid  = threadIdx.x;
  const int lane = tid & 63;
  const int wid  = tid >> 6;
  const int wm = wid >> 2, wn = wid & 3;  // 2M x 4N, wave-out 64x64
  const int lm = lane & 15, lk = lane >> 4, lr = lane >> 4;
  const int wlds = (tid & ~63) * 8;

  const short* Ab  = xf + (size_t)bt*32*8192;
  const short* Bb0 = w1f + (size_t)(2*nt)*32*8192;
  const short* Bb1 = w1f + (size_t)(2*nt+1)*32*8192;

  f32x4 acc[4][4] = {};

  // ---- core: NKT=32 K-tiles, 2 sub-phases each, 3 loads/sub-phase ----
  auto STAGE = [&](int n2) {
    const int tau = n2 >> 1, ks = n2 & 1, b = tau & 1;
    gload_lds16(Ab  + (size_t)tau*8192 + ks*4096 + tid*8,
                lds + b*24576 + ks*4096 + wlds);
    gload_lds16(Bb0 + (size_t)tau*8192 + ks*4096 + tid*8,
                lds + b*24576 + 8192 + ks*4096 + wlds);
    gload_lds16(Bb1 + (size_t)tau*8192 + ks*4096 + tid*8,
                lds + b*24576 + 16384 + ks*4096 + wlds);
  };

  STAGE(0); STAGE(1);
  VMCNT(3); BAR();

  for (int n = 0; n < 64; ++n) {
    const int tau = n >> 1, ks = n & 1, b = tau & 1;
    if (n + 2 < 64) STAGE(n + 2);
    short8 av[4], bv[4];
    #pragma unroll
    for (int f = 0; f < 4; ++f)
      av[f] = *(const short8*)(lds + b*24576 + (ks*4+lk)*1024 + (wm*64 + f*16 + lm)*8);
    #pragma unroll
    for (int f = 0; f < 4; ++f)
      bv[f] = *(const short8*)(lds + b*24576 + 8192 + (wn>>1)*8192 + (ks*4+lk)*1024
                               + ((wn&1)*64 + f*16 + lm)*8);
    #pragma unroll
    for (int i = 0; i < 4; ++i)
      #pragma unroll
      for (int j = 0; j < 4; ++j)
        acc[i][j] = __builtin_amdgcn_mfma_f32_16x16x32_bf16(av[i], bv[j], acc[i][j], 0, 0, 0);
    if (n + 2 < 64)      { VMCNT(3); BAR(); }
    else if (n + 1 < 64) { VMCNT(0); BAR(); }
  }
  BAR();   // all waves done reading core bufs

  // ---- epilogue: stage W2 pair, write silu(h1) to LDS frag-ready ----
  // regions: h1 @ [0,32768) shorts  [eh][kt2][kg][p][j]
  //          W2 @ [32768,65536)     [eh][kt2][kg][p][j]
  #pragma unroll
  for (int q = 0; q < 8; ++q)
    gload_lds16(w2f + (size_t)nt*32768 + q*4096 + tid*8, lds + 32768 + q*4096 + wlds);

  float b1v[4];
  #pragma unroll
  for (int fn = 0; fn < 4; ++fn) b1v[fn] = b1[nt*256 + wn*64 + fn*16 + lm];
  #pragma unroll
  for (int fm = 0; fm < 4; ++fm)
  #pragma unroll
  for (int i = 0; i < 4; ++i) {
    const int m = wm*64 + fm*16 + lr*4 + i;          // 0..127
    #pragma unroll
    for (int fn = 0; fn < 4; ++fn) {
      const int n = wn*64 + fn*16 + lm;              // 0..255
      const float v = silu_f(acc[fm][fn][i] + b1v[fn]);
      lds[(n>>7)*16384 + ((n>>6)&1)*8192 + ((n>>3)&7)*1024 + m*8 + (n&7)] = f2bf(v);
    }
  }
  VMCNT(0); BAR();   // h1 + W2 ready

  // ---- GEMM2 pass per expert-half: out 128x128, 8 waves 2Mx4N (64x32) ----
  const int wm2 = wid >> 2, wn2 = wid & 3;
  #pragma unroll
  for (int eh = 0; eh < 2; ++eh) {
    f32x4 acc2[4][2] = {};
    #pragma unroll
    for (int kt2 = 0; kt2 < 2; ++kt2)
    #pragma unroll
    for (int ks = 0; ks < 2; ++ks) {
      short8 a2[4], b2v[2];
      #pragma unroll
      for (int f = 0; f < 4; ++f)
        a2[f] = *(const short8*)(lds + eh*16384 + kt2*8192 + (ks*4+lk)*1024
                                 + (wm2*64 + f*16 + lm)*8);
      #pragma unroll
      for (int f = 0; f < 2; ++f)
        b2v[f] = *(const short8*)(lds + 32768 + eh*16384 + kt2*8192 + (ks*4+lk)*1024
                                  + (wn2*32 + f*16 + lm)*8);
      #pragma unroll
      for (int i = 0; i < 4; ++i)
        #pragma unroll
        for (int j = 0; j < 2; ++j)
          acc2[i][j] = __builtin_amdgcn_mfma_f32_16x16x32_bf16(a2[i], b2v[j], acc2[i][j], 0, 0, 0);
    }
    BAR();   // all waves done reading W2[eh] region before overwrite

    const int e = 2*nt + eh;
    #pragma unroll
    for (int fm = 0; fm < 4; ++fm)
    #pragma unroll
    for (int i = 0; i < 4; ++i) {
      const int m = wm2*64 + fm*16 + lr*4 + i;       // 0..127
      const float g = gates[(size_t)(bt*128 + m)*8 + e];
      #pragma unroll
      for (int fn = 0; fn < 2; ++fn) {
        const int h = wn2*32 + fn*16 + lm;           // 0..127
        const float v = silu_f(acc2[fm][fn][i] + b2[e*128 + h]) * g;
        lds[32768 + ((h>>6)&1)*8192 + ((h>>3)&7)*1024 + m*8 + (h&7)] = f2bf(v);
      }
    }
    BAR();
    // dump 32KB h2[eh] -> h2gf tiles (bt*16 + 2e + t2)
    #pragma unroll
    for (int q = 0; q < 4; ++q) {
      const int li = q*4096 + tid*8;
      const int t2 = li >> 13, o = li & 8191;
      *(short8*)(h2gf + ((size_t)bt*16 + 2*e + t2)*8192 + o) =
          *(const short8*)(lds + 32768 + li);
    }
    if (eh == 0) BAR();  // dump reads done before h2[1] overwrites region
  }
}

// ---------------------------------------------------------------------------
// K4: out = h2g @ W3flat + gates @ b3.  BM=BN=256, K=1024.  512 thr, 8 waves
// (2Mx4N), wave-out 128x64, acc[8][4].  LDS 128KB (2 x 64KB tile bufs).
// grid: 256 blocks, XCD-chunked: bt=xcd*4+(idx&3) (0..31), nt=idx>>2 (0..7).
// ---------------------------------------------------------------------------
__global__ __launch_bounds__(512, 2)
void k_gemm3(const short* __restrict__ h2gf, const short* __restrict__ w3f,
             const float* __restrict__ b3, const float* __restrict__ gates,
             float* __restrict__ out)
{
  __shared__ short lds[65536];   // 128 KB
  const int wg = blockIdx.x;
  const int xcd = wg & 7, idx = wg >> 3;
  const int bt = xcd*4 + (idx & 3);       // 0..31 (A panels L2-resident per XCD)
  const int nt = idx >> 2;                // 0..7

  const int tid  = threadIdx.x;
  const int lane = tid & 63;
  const int wid  = tid >> 6;
  const int wm = wid >> 2, wn = wid & 3;  // wave-out 128x64
  const int lm = lane & 15, lk = lane >> 4, lr = lane >> 4;
  const int wlds = (tid & ~63) * 8;

  const short* A0 = h2gf + (size_t)(bt*2)*16*8192;
  const short* A1 = h2gf + (size_t)(bt*2+1)*16*8192;
  const short* B0 = w3f + (size_t)(2*nt)*16*8192;
  const short* B1 = w3f + (size_t)(2*nt+1)*16*8192;

  f32x4 acc[8][4] = {};

  auto STAGE = [&](int n2) {
    const int tau = n2 >> 1, ks = n2 & 1, b = tau & 1;
    gload_lds16(A0 + (size_t)tau*8192 + ks*4096 + tid*8,
                lds + b*32768 + ks*4096 + wlds);
    gload_lds16(A1 + (size_t)tau*8192 + ks*4096 + tid*8,
                lds + b*32768 + 8192 + ks*4096 + wlds);
    gload_lds16(B0 + (size_t)tau*8192 + ks*4096 + tid*8,
                lds + b*32768 + 16384 + ks*4096 + wlds);
    gload_lds16(B1 + (size_t)tau*8192 + ks*4096 + tid*8,
                lds + b*32768 + 24576 + ks*4096 + wlds);
  };

  STAGE(0); STAGE(1);
  VMCNT(4); BAR();

  for (int n = 0; n < 32; ++n) {
    const int tau = n >> 1, ks = n & 1, b = tau & 1;
    if (n + 2 < 32) STAGE(n + 2);
    short8 av[8], bv[4];
    #pragma unroll
    for (int f = 0; f < 8; ++f)
      av[f] = *(const short8*)(lds + b*32768 + wm*8192 + (ks*4+lk)*1024 + (f*16 + lm)*8);
    #pragma unroll
    for (int f = 0; f < 4; ++f)
      bv[f] = *(const short8*)(lds + b*32768 + 16384 + (wn>>1)*8192 + (ks*4+lk)*1024
                               + ((wn&1)*64 + f*16 + lm)*8);
    #pragma unroll
    for (int i = 0; i < 8; ++i)
      #pragma unroll
      for (int j = 0; j < 4; ++j)
        acc[i][j] = __builtin_amdgcn_mfma_f32_16x16x32_bf16(av[i], bv[j], acc[i][j], 0, 0, 0);
    if (n + 2 < 32)      { VMCNT(4); BAR(); }
    else if (n + 1 < 32) { VMCNT(0); BAR(); }
  }

  // ---- epilogue: bias (gates @ b3) + store fp32 ----
  float b3c[4][8];
  #pragma unroll
  for (int fn = 0; fn < 4; ++fn) {
    const int n = nt*256 + wn*64 + fn*16 + lm;
    #pragma unroll
    for (int e = 0; e < 8; ++e) b3c[fn][e] = b3[(size_t)e*D_SZ + n];
  }
  #pragma unroll
  for (int fm = 0; fm < 8; ++fm)
  #pragma unroll
  for (int i = 0; i < 4; ++i) {
    const int m = bt*256 + wm*128 + fm*16 + lr*4 + i;
    const float4 ga  = *(const float4*)(gates + (size_t)m*8);
    const float4 gbv = *(const float4*)(gates + (size_t)m*8 + 4);
    #pragma unroll
    for (int fn = 0; fn < 4; ++fn) {
      const int n = nt*256 + wn*64 + fn*16 + lm;
      const float bias = ga.x*b3c[fn][0] + ga.y*b3c[fn][1] + ga.z*b3c[fn][2] + ga.w*b3c[fn][3]
                       + gbv.x*b3c[fn][4] + gbv.y*b3c[fn][5] + gbv.z*b3c[fn][6] + gbv.w*b3c[fn][7];
      out[(size_t)m*D_SZ + n] = acc[fm][fn][i] + bias;
    }
  }
}

// ---------------------------------------------------------------------------
extern "C" void kernel_launch(void* const* d_in, const int* in_sizes, int n_in,
                              void* d_out, int out_size, void* d_ws, size_t ws_size,
                              hipStream_t stream)
{
  (void)in_sizes; (void)n_in; (void)out_size; (void)ws_size;
  const float* x  = (const float*)d_in[0];
  const float* gw = (const float*)d_in[1];
  const float* gb = (const float*)d_in[2];
  const float* W1 = (const float*)d_in[3];
  const float* b1 = (const float*)d_in[4];
  const float* W2 = (const float*)d_in[5];
  const float* b2 = (const float*)d_in[6];
  const float* W3 = (const float*)d_in[7];
  const float* b3 = (const float*)d_in[8];
  float* out = (float*)d_out;

  char* ws = (char*)d_ws;
  short* xf    = (short*)ws;  ws += (size_t)B_SZ*D_SZ*2;          // 33.5 MB
  short* w1f   = (short*)ws;  ws += (size_t)E_SZ*D_SZ*H_SZ*2;     //  4.2 MB
  short* w2f   = (short*)ws;  ws += (size_t)E_SZ*H_SZ*H_SZ*2;     //  0.26 MB
  short* w3f   = (short*)ws;  ws += (size_t)E_SZ*H_SZ*D_SZ*2;     //  4.2 MB
  float* gates = (float*)ws;  ws += (size_t)B_SZ*E_SZ*4;          //  0.26 MB
  short* h2gf  = (short*)ws;  ws += (size_t)B_SZ*E_SZ*H_SZ*2;     // 16.8 MB

  k_convert<<<dim3(10304), dim3(256), 0, stream>>>(x, W1, W2, W3, xf, w1f, w2f, w3f);
  k_gate   <<<dim3(2048),  dim3(256), 0, stream>>>(x, gw, gb, gates);
  k_gemm12 <<<dim3(256), dim3(512), 0, stream>>>(xf, w1f, w2f, b1, b2, gates, h2gf);
  k_gemm3  <<<dim3(256), dim3(512), 0, stream>>>(h2gf, w3f, b3, gates, out);
}